// Round 5
// baseline (317.464 us; speedup 1.0000x reference)
//
#include <hip/hip_runtime.h>
#include <hip/hip_fp16.h>

#define BS     4
#define NQ     10000
#define NV     13294
#define EMBED  256
#define HEADS  8
#define LEVELS 4
#define POINTS 4
#define DH     32

// padded row counts (multiples of 128) so GEMM A-tiles can be read unguarded
#define MV_PAD 53248   // ceil(4*13294/128)*128
#define MQ_PAD 40064   // ceil(4*10000/128)*128

typedef __attribute__((ext_vector_type(8))) _Float16 half8;
typedef __attribute__((ext_vector_type(4))) float floatx4;

static __device__ __forceinline__ unsigned short f2h(float f) {
    __half h = __float2half(f);   // RNE
    return *(unsigned short*)&h;
}
static __device__ __forceinline__ float h2f(unsigned short u) {
    __half h = *(__half*)&u;
    return __half2float(h);
}
static __device__ __forceinline__ unsigned int pk_f16(float x, float y) {
    __half2 h = __floats2half2_rn(x, y);
    unsigned int u; __builtin_memcpy(&u, &h, 4); return u;
}

// async global->LDS, 16B per lane. LDS dest is wave-uniform base + lane*16.
static __device__ __forceinline__ void gload_lds16(const unsigned short* g, unsigned short* l) {
    __builtin_amdgcn_global_load_lds(
        (const __attribute__((address_space(1))) void*)g,
        (__attribute__((address_space(3))) void*)l,
        16, 0, 0);
}

// ---------------------------------------------------------------------------
// prep_convert:
//  blocks [0,896): weight transpose+cast (f16)
//  blocks [896, 896+CONV_BLOCKS): streaming fp32->f16 of value and query
// ---------------------------------------------------------------------------
#define CONV_BLOCKS 2048

__global__ __launch_bounds__(256) void prep_convert(
    const float* __restrict__ Wv,  const float* __restrict__ Woff,
    const float* __restrict__ boff,const float* __restrict__ Ww,
    const float* __restrict__ bw,  const float* __restrict__ Wo,
    const float* __restrict__ value, const float* __restrict__ query,
    unsigned short* __restrict__ Wvt, unsigned short* __restrict__ Wcatt,
    unsigned short* __restrict__ Wot, float* __restrict__ bcat,
    unsigned short* __restrict__ v16, unsigned short* __restrict__ q16)
{
    const int n = blockIdx.x;
    const int k = threadIdx.x;   // 0..255
    if (n < 896) {
        if (n < 256) {
            Wvt[n * 256 + k] = f2h(Wv[k * 256 + n]);
        } else if (n < 512) {
            Wcatt[(n - 256) * 256 + k] = f2h(Woff[k * 256 + (n - 256)]);
        } else if (n < 640) {
            Wcatt[(n - 256) * 256 + k] = f2h(Ww[k * 128 + (n - 512)]);
        } else {
            Wot[(n - 640) * 256 + k] = f2h(Wo[k * 256 + (n - 640)]);
        }
        if (n == 0) {
            for (int j = k; j < 384; j += 256)
                bcat[j] = (j < 256) ? boff[j] : bw[j - 256];
        }
        return;
    }
    // convert in units of 8 floats (two float4 loads -> one uint4 store)
    const long long NV8 = (long long)BS * NV * 256 / 8;   // 1,701,632
    const long long NQ8 = (long long)BS * NQ * 256 / 8;   // 1,280,000
    const long long stride = (long long)CONV_BLOCKS * 256;
    for (long long u = (long long)(n - 896) * 256 + k; u < NV8 + NQ8; u += stride) {
        const float4* s;
        unsigned short* d;
        if (u < NV8) { s = (const float4*)value + u * 2;         d = v16 + u * 8; }
        else         { s = (const float4*)query + (u - NV8) * 2; d = q16 + (u - NV8) * 8; }
        const float4 f0 = s[0], f1 = s[1];
        uint4 o;
        o.x = pk_f16(f0.x, f0.y);
        o.y = pk_f16(f0.z, f0.w);
        o.z = pk_f16(f1.x, f1.y);
        o.w = pk_f16(f1.z, f1.w);
        *(uint4*)d = o;
    }
}

// ---------------------------------------------------------------------------
// f16 MFMA GEMM body: C[M x N] = A[M x 256] @ Bt^T + bias (all f16 inputs).
// 128x128 tile / 256 threads / BK=64. m97 structure: global_load_lds width-16
// staging into linear LDS. Rule-21 both-sides XOR swizzle.
// MODE 0: f16 out row-major; 2: fp32 out + residual;
// MODE 3: f16 out scattered to per-head layout [(b*8+h)*NV + s]*32 + d.
// ---------------------------------------------------------------------------
template<int MODE>
static __device__ __forceinline__ void gemm_body(
    unsigned short* As, unsigned short* Bs,
    const unsigned short* __restrict__ A, int M,
    const unsigned short* __restrict__ Bt,
    const float* __restrict__ bias,
    void* __restrict__ Cv, int ldc,
    const float* __restrict__ residual,
    int mb, int nb)
{
    const int t    = threadIdx.x;
    const int w    = t >> 6;
    const int lane = t & 63;
    const int m0 = mb * 128;
    const int n0 = nb * 128;
    const int wm = (w & 1) * 64;
    const int wn = (w >> 1) * 64;
    const int lr = lane & 15;
    const int lk = (lane >> 4) * 8;

    // staging geometry: wave w, issue j covers LDS rows w*8+j*32 .. +8;
    // lane covers row w*8+j*32+(lane>>3), 16B chunk (lane&7).
    // Source column chunk pre-swizzled: chunk (lane&7)^(row&7), row&7=lane>>3.
    const int srow = w * 8 + (lane >> 3);
    const int scol = ((lane & 7) ^ (lane >> 3)) * 8;
    const unsigned short* ga = A  + (size_t)(m0 + srow) * 256 + scol;
    const unsigned short* gb = Bt + (size_t)(n0 + srow) * 256 + scol;
    unsigned short* lA = As + w * 512;   // + j*2048
    unsigned short* lB = Bs + w * 512;

    floatx4 acc[4][4] = {};

    for (int k0 = 0; k0 < 256; k0 += 64) {
        __syncthreads();   // previous tile's LDS reads complete before overwrite
        #pragma unroll
        for (int j = 0; j < 4; ++j) {
            gload_lds16(ga + (size_t)j * 32 * 256 + k0, lA + j * 2048);
            gload_lds16(gb + (size_t)j * 32 * 256 + k0, lB + j * 2048);
        }
        __syncthreads();   // vmcnt(0) drain: tile resident in LDS

        #pragma unroll
        for (int kk = 0; kk < 64; kk += 32) {
            half8 bf[4];
            #pragma unroll
            for (int nt = 0; nt < 4; ++nt) {
                const int row = wn + nt * 16 + lr;
                const int cb  = ((kk + lk) * 2) ^ ((row & 7) << 4);
                bf[nt] = *(const half8*)((const char*)Bs + row * 128 + cb);
            }
            #pragma unroll
            for (int mt = 0; mt < 4; ++mt) {
                const int row = wm + mt * 16 + lr;
                const int cb  = ((kk + lk) * 2) ^ ((row & 7) << 4);
                const half8 af = *(const half8*)((const char*)As + row * 128 + cb);
                #pragma unroll
                for (int nt = 0; nt < 4; ++nt)
                    acc[mt][nt] = __builtin_amdgcn_mfma_f32_16x16x32_f16(af, bf[nt], acc[mt][nt], 0, 0, 0);
            }
        }
    }

    // epilogue: C/D layout col = lane&15, row = (lane>>4)*4 + reg
    const int rbase = m0 + wm + (lane >> 4) * 4;
    #pragma unroll
    for (int nt = 0; nt < 4; ++nt) {
        const int col = n0 + wn + nt * 16 + lr;
        const float bb_ = bias[col];
        #pragma unroll
        for (int mt = 0; mt < 4; ++mt) {
            #pragma unroll
            for (int r = 0; r < 4; ++r) {
                const int row = rbase + mt * 16 + r;
                if (row < M) {
                    float val = acc[mt][nt][r] + bb_;
                    if (MODE == 2) val += residual[(size_t)row * ldc + col];
                    if (MODE == 0) {
                        ((unsigned short*)Cv)[(size_t)row * ldc + col] = f2h(val);
                    } else if (MODE == 3) {
                        const int b_ = row / NV;
                        const int s_ = row - b_ * NV;
                        const int h_ = col >> 5, d_ = col & 31;
                        ((unsigned short*)Cv)[(((size_t)b_ * 8 + h_) * NV + s_) * 32 + d_] = f2h(val);
                    } else {
                        ((float*)Cv)[(size_t)row * ldc + col] = val;
                    }
                }
            }
        }
    }
}

// Fused GEMM-V + GEMM-proj (independent, one dispatch to fill the machine).
//   [0, 832): v = v16 @ Wv + bv  -> per-head layout   (416 m x 2 n)
//   [832,1771): proj = q16 @ Wcat + bcat (row-major)  (313 m x 3 n)
// Bijective chunked XCD swizzle (m204).
__global__ __launch_bounds__(256) void gemm_fused12(
    const unsigned short* __restrict__ v16, const unsigned short* __restrict__ q16,
    const unsigned short* __restrict__ Wvt, const unsigned short* __restrict__ Wcatt,
    const float* __restrict__ bv, const float* __restrict__ bcat,
    unsigned short* __restrict__ vout, unsigned short* __restrict__ projout)
{
    __shared__ __align__(16) unsigned short As[128 * 64];
    __shared__ __align__(16) unsigned short Bs[128 * 64];
    // nwg = 1771: q = 221, r = 3
    const unsigned int xcd = blockIdx.x & 7u, kk = blockIdx.x >> 3;
    const unsigned int wg = (xcd < 3u ? xcd * 222u : 3u * 222u + (xcd - 3u) * 221u) + kk;
    if (wg < 832u) {
        gemm_body<3>(As, Bs, v16, BS * NV, Wvt, bv, vout, 256, nullptr,
                     (int)(wg >> 1), (int)(wg & 1));
    } else {
        const unsigned int b2 = wg - 832u;
        gemm_body<0>(As, Bs, q16, BS * NQ, Wcatt, bcat, projout, 384, nullptr,
                     (int)(b2 / 3u), (int)(b2 % 3u));
    }
}

// out = msda @ Wo + bo + query  (fp32 out). 1D grid 626 + chunked swizzle.
__global__ __launch_bounds__(256) void gemm_out(
    const unsigned short* __restrict__ msda, const unsigned short* __restrict__ Wot,
    const float* __restrict__ bo, float* __restrict__ out,
    const float* __restrict__ query)
{
    __shared__ __align__(16) unsigned short As[128 * 64];
    __shared__ __align__(16) unsigned short Bs[128 * 64];
    // nwg = 626: q = 78, r = 2
    const unsigned int xcd = blockIdx.x & 7u, kk = blockIdx.x >> 3;
    const unsigned int wg = (xcd < 2u ? xcd * 79u : 2u * 79u + (xcd - 2u) * 78u) + kk;
    gemm_body<2>(As, Bs, msda, BS * NQ, Wot, bo, out, 256, query,
                 (int)(wg >> 1), (int)(wg & 1));
}

// ---------------------------------------------------------------------------
// Fused softmax + bilinear sampling, head-partitioned for XCD-local L2.
// One block = one (b,h) x 32 queries. blockIdx.x % 8 == h pins head h to
// XCD h (HW round-robin) -> per-XCD gather working set = 4b x NV x 64B
// = 3.4 MB < 4 MB L2. v is the per-head layout [b][h][NV][32] (f16).
// Wave = 8 queries; lane = q'*8+i. Tap entry (16 B):
// {off_tap0, off_tap1, pk(w0,w0), pk(w1,w1)}; phase B accumulates in packed
// f16-pair space via v_pk_fma_f16. Taps per-wave -> lgkm drain only.
// ---------------------------------------------------------------------------
__global__ __launch_bounds__(256) void msda_sample(
    const unsigned short* __restrict__ v,
    const unsigned short* __restrict__ proj,
    const float* __restrict__ rp,
    unsigned short* __restrict__ out)
{
    __shared__ __align__(16) unsigned int taps[4 * 1056];  // 4 waves * 8 q * 528 B

    const unsigned int bid = blockIdx.x;
    const int h      = (int)(bid & 7u);          // -> XCD h
    const int b      = (int)((bid >> 3) & 3u);
    const int qchunk = (int)(bid >> 5);          // [0,313)
    const int wave = threadIdx.x >> 6;
    const int lane = threadIdx.x & 63;
    const int qi   = lane >> 3;                  // query slot within wave
    const int li   = lane & 7;
    const int q    = qchunk * 32 + wave * 8 + qi;
    const bool qok = q < NQ;
    const int rowq = b * NQ + (qok ? q : 0);
    const unsigned short* prow = proj + (size_t)rowq * 384;

    // ---- phase A: lane owns combos c = 2*li, 2*li+1 of (q, h) ----
    const int c0 = li * 2;

    const ushort2 lgu = *(const ushort2*)&prow[256 + h * 16 + c0];
    const float lgx = h2f(lgu.x), lgy = h2f(lgu.y);
    float mx = fmaxf(lgx, lgy);
    mx = fmaxf(mx, __shfl_xor(mx, 1));
    mx = fmaxf(mx, __shfl_xor(mx, 2));
    mx = fmaxf(mx, __shfl_xor(mx, 4));
    const float e0 = __expf(lgx - mx);
    const float e1 = __expf(lgy - mx);
    float ssum = e0 + e1;
    ssum += __shfl_xor(ssum, 1);
    ssum += __shfl_xor(ssum, 2);
    ssum += __shfl_xor(ssum, 4);
    const float inv = 1.0f / ssum;

    const int l = c0 >> 2;   // both combos share the level
    const int Wl = (l == 0) ? 100 : (l == 1) ? 50 : (l == 2) ? 25 : 13;
    const int st = (l == 0) ? 0 : (l == 1) ? 10000 : (l == 2) ? 12500 : 13125;
    const int Hl = Wl;
    const float fW = (float)Wl, fH = (float)Hl;

    const float2 rxy = *(const float2*)&rp[((size_t)rowq * 4 + l) * 2];

    unsigned int* tbase = taps + wave * 1056 + qi * 132;

    #pragma unroll
    for (int cc = 0; cc < 2; ++cc) {
        const int c = c0 + cc;
        const ushort2 oxyu = *(const ushort2*)&prow[h * 32 + c * 2];
        const float ox = h2f(oxyu.x), oy = h2f(oxyu.y);
        const float aww = (cc ? e1 : e0) * inv;
        const float x = fmaf(rxy.x, fW, ox) - 0.5f;
        const float y = fmaf(rxy.y, fH, oy) - 0.5f;
        const float x0f = floorf(x), y0f = floorf(y);
        const float fx = x - x0f, fy = y - y0f;
        const int ix = (int)x0f, iy = (int)y0f;
        const float wxv[2] = {1.f - fx, fx};
        const float wyv[2] = {1.f - fy, fy};

        unsigned int offv[4]; float wv_[4];
        #pragma unroll
        for (int tp = 0; tp < 4; ++tp) {
            const int dy = tp >> 1, dx = tp & 1;
            const int xi = ix + dx, yi = iy + dy;
            const bool ok = (xi >= 0) && (xi < Wl) && (yi >= 0) && (yi < Hl);
            const int cx = min(max(xi, 0), Wl - 1);
            const int cy = min(max(yi, 0), Hl - 1);
            offv[tp] = (unsigned int)(st + cy * Wl + cx) * 64u;   // bytes in (b,h) sub-table
            wv_[tp]  = ok ? wyv[dy] * wxv[dx] * aww : 0.f;
        }
        const uint4 e0v = make_uint4(offv[0], offv[1], pk_f16(wv_[0], wv_[0]), pk_f16(wv_[1], wv_[1]));
        const uint4 e1v = make_uint4(offv[2], offv[3], pk_f16(wv_[2], wv_[2]), pk_f16(wv_[3], wv_[3]));
        *(uint4*)&tbase[c * 8]     = e0v;
        *(uint4*)&tbase[c * 8 + 4] = e1v;
    }

    // per-wave LDS drain (taps produced and consumed by this wave only)
    asm volatile("s_waitcnt lgkmcnt(0)" ::: "memory");

    // ---- phase B: lane = qi*8+li owns dims li*4..li*4+3 of (q, h) ----
    const unsigned int lane_off = (unsigned int)li * 8u;
    const char* vbase = (const char*)v + ((size_t)b * 8 + h) * (size_t)NV * 64;
    const uint4* tp4 = (const uint4*)(taps + wave * 1056 + qi * 132);

    __half2 a01 = __floats2half2_rn(0.f, 0.f);
    __half2 a23 = __floats2half2_rn(0.f, 0.f);
    #pragma unroll 8
    for (int j = 0; j < 32; ++j) {
        const uint4 ee = tp4[j];
        const uint2 g0 = *(const uint2*)(vbase + (ee.x + lane_off));
        const uint2 g1 = *(const uint2*)(vbase + (ee.y + lane_off));
        __half2 w0, w1, v0, v1, v2, v3;
        __builtin_memcpy(&w0, &ee.z, 4);
        __builtin_memcpy(&w1, &ee.w, 4);
        __builtin_memcpy(&v0, &g0.x, 4);
        __builtin_memcpy(&v1, &g0.y, 4);
        __builtin_memcpy(&v2, &g1.x, 4);
        __builtin_memcpy(&v3, &g1.y, 4);
        a01 = __hfma2(v0, w0, a01);
        a23 = __hfma2(v1, w0, a23);
        a01 = __hfma2(v2, w1, a01);
        a23 = __hfma2(v3, w1, a23);
    }

    if (qok) {
        uint2 o;
        __builtin_memcpy(&o.x, &a01, 4);
        __builtin_memcpy(&o.y, &a23, 4);
        *(uint2*)&out[(size_t)rowq * 256 + h * 32 + li * 4] = o;
    }
}

// ---------------------------------------------------------------------------
// kernel_launch
// ---------------------------------------------------------------------------
extern "C" void kernel_launch(void* const* d_in, const int* in_sizes, int n_in,
                              void* d_out, int out_size, void* d_ws, size_t ws_size,
                              hipStream_t stream) {
    const float* query = (const float*)d_in[0];
    const float* value = (const float*)d_in[1];
    const float* rp    = (const float*)d_in[2];
    const float* Wv    = (const float*)d_in[4];
    const float* bv    = (const float*)d_in[5];
    const float* Woff  = (const float*)d_in[6];
    const float* boff  = (const float*)d_in[7];
    const float* Ww    = (const float*)d_in[8];
    const float* bw    = (const float*)d_in[9];
    const float* Wo    = (const float*)d_in[10];
    const float* bo    = (const float*)d_in[11];
    float* out = (float*)d_out;

    const int Mq = BS * NQ;   // 40000

    char* ws = (char*)d_ws;
    const size_t SZ_MSDA = (size_t)MQ_PAD * 256 * 2;   // padded rows
    const size_t SZ_VIN  = (size_t)MV_PAD * 256 * 2;   // f16 value, padded
    const size_t SZ_QIN  = (size_t)MQ_PAD * 256 * 2;   // f16 query, padded
    const size_t SZ_VPR  = (size_t)BS * NV * 256 * 2;  // projected v (per-head layout)
    const size_t SZ_PROJ = (size_t)Mq * 384 * 2;

    unsigned short* msda  = (unsigned short*)(ws);
    unsigned short* v16   = (unsigned short*)(ws + SZ_MSDA);
    unsigned short* q16   = (unsigned short*)(ws + SZ_MSDA + SZ_VIN);
    unsigned short* v_prj = (unsigned short*)(ws + SZ_MSDA + SZ_VIN + SZ_QIN);
    unsigned short* proj  = (unsigned short*)(ws + SZ_MSDA + SZ_VIN + SZ_QIN + SZ_VPR);
    char* wp = ws + SZ_MSDA + SZ_VIN + SZ_QIN + SZ_VPR + SZ_PROJ;
    unsigned short* Wvt   = (unsigned short*)(wp);
    unsigned short* Wcatt = (unsigned short*)(wp + 256 * 256 * 2);
    unsigned short* Wot   = (unsigned short*)(wp + 256 * 256 * 2 + 384 * 256 * 2);
    float*          bcat  = (float*)(wp + 256 * 256 * 2 + 384 * 256 * 2 + 256 * 256 * 2);

    // weights transpose/cast + value/query fp32->f16 streaming convert
    prep_convert<<<896 + CONV_BLOCKS, 256, 0, stream>>>(
        Wv, Woff, boff, Ww, bw, Wo, value, query,
        Wvt, Wcatt, Wot, bcat, v16, q16);

    // v_prj = v16 @ Wv + bv (f16, per-head layout) AND proj = q16 @ Wcat + bcat
    gemm_fused12<<<832 + 939, 256, 0, stream>>>(
        v16, q16, Wvt, Wcatt, bv, bcat, v_prj, proj);

    // softmax + sampling -> msda (f16). 313 qchunks x 4 b x 8 h, h = bid%8.
    msda_sample<<<313 * 32, 256, 0, stream>>>(v_prj, proj, rp, msda);

    // out = msda @ Wo + bo + query
    gemm_out<<<626, 256, 0, stream>>>(msda, Wot, bo, out, query);
}

// Round 6
// 288.048 us; speedup vs baseline: 1.1021x; 1.1021x over previous
//
#include <hip/hip_runtime.h>
#include <hip/hip_fp16.h>

#define BS     4
#define NQ     10000
#define NV     13294
#define EMBED  256
#define HEADS  8
#define LEVELS 4
#define POINTS 4
#define DH     32

// padded row counts (multiples of 128) so GEMM A-tiles can be read unguarded
#define MV_PAD 53248   // ceil(4*13294/128)*128
#define MQ_PAD 40064   // ceil(4*10000/128)*128

typedef __attribute__((ext_vector_type(8))) _Float16 half8;
typedef __attribute__((ext_vector_type(4))) float floatx4;

static __device__ __forceinline__ unsigned short f2h(float f) {
    __half h = __float2half(f);   // RNE
    return *(unsigned short*)&h;
}
static __device__ __forceinline__ float h2f(unsigned short u) {
    __half h = *(__half*)&u;
    return __half2float(h);
}
static __device__ __forceinline__ unsigned int pk_f16(float x, float y) {
    __half2 h = __floats2half2_rn(x, y);
    unsigned int u; __builtin_memcpy(&u, &h, 4); return u;
}

// async global->LDS, 16B per lane. LDS dest is wave-uniform base + lane*16.
static __device__ __forceinline__ void gload_lds16(const unsigned short* g, unsigned short* l) {
    __builtin_amdgcn_global_load_lds(
        (const __attribute__((address_space(1))) void*)g,
        (__attribute__((address_space(3))) void*)l,
        16, 0, 0);
}

// ---------------------------------------------------------------------------
// prep_convert:
//  blocks [0,896): weight transpose+cast (f16)
//  blocks [896, 896+CONV_BLOCKS): streaming fp32->f16 of value and query
// ---------------------------------------------------------------------------
#define CONV_BLOCKS 2048

__global__ __launch_bounds__(256) void prep_convert(
    const float* __restrict__ Wv,  const float* __restrict__ Woff,
    const float* __restrict__ boff,const float* __restrict__ Ww,
    const float* __restrict__ bw,  const float* __restrict__ Wo,
    const float* __restrict__ value, const float* __restrict__ query,
    unsigned short* __restrict__ Wvt, unsigned short* __restrict__ Wcatt,
    unsigned short* __restrict__ Wot, float* __restrict__ bcat,
    unsigned short* __restrict__ v16, unsigned short* __restrict__ q16)
{
    const int n = blockIdx.x;
    const int k = threadIdx.x;   // 0..255
    if (n < 896) {
        if (n < 256) {
            Wvt[n * 256 + k] = f2h(Wv[k * 256 + n]);
        } else if (n < 512) {
            Wcatt[(n - 256) * 256 + k] = f2h(Woff[k * 256 + (n - 256)]);
        } else if (n < 640) {
            Wcatt[(n - 256) * 256 + k] = f2h(Ww[k * 128 + (n - 512)]);
        } else {
            Wot[(n - 640) * 256 + k] = f2h(Wo[k * 256 + (n - 640)]);
        }
        if (n == 0) {
            for (int j = k; j < 384; j += 256)
                bcat[j] = (j < 256) ? boff[j] : bw[j - 256];
        }
        return;
    }
    // convert in units of 8 floats (two float4 loads -> one uint4 store)
    const long long NV8 = (long long)BS * NV * 256 / 8;   // 1,701,632
    const long long NQ8 = (long long)BS * NQ * 256 / 8;   // 1,280,000
    const long long stride = (long long)CONV_BLOCKS * 256;
    for (long long u = (long long)(n - 896) * 256 + k; u < NV8 + NQ8; u += stride) {
        const float4* s;
        unsigned short* d;
        if (u < NV8) { s = (const float4*)value + u * 2;         d = v16 + u * 8; }
        else         { s = (const float4*)query + (u - NV8) * 2; d = q16 + (u - NV8) * 8; }
        const float4 f0 = s[0], f1 = s[1];
        uint4 o;
        o.x = pk_f16(f0.x, f0.y);
        o.y = pk_f16(f0.z, f0.w);
        o.z = pk_f16(f1.x, f1.y);
        o.w = pk_f16(f1.z, f1.w);
        *(uint4*)d = o;
    }
}

// ---------------------------------------------------------------------------
// f16 MFMA GEMM body: C[M x N] = A[M x 256] @ Bt^T + bias (all f16 inputs).
// 128x128 tile / 256 threads / BK=64. m97 structure: global_load_lds width-16
// staging into linear LDS. Rule-21 both-sides XOR swizzle.
// MODE 0: f16 out row-major; 2: fp32 out + residual;
// MODE 3: f16 out scattered to per-head layout [(b*8+h)*NV + s]*32 + d.
// ---------------------------------------------------------------------------
template<int MODE>
static __device__ __forceinline__ void gemm_body(
    unsigned short* As, unsigned short* Bs,
    const unsigned short* __restrict__ A, int M,
    const unsigned short* __restrict__ Bt,
    const float* __restrict__ bias,
    void* __restrict__ Cv, int ldc,
    const float* __restrict__ residual,
    int mb, int nb)
{
    const int t    = threadIdx.x;
    const int w    = t >> 6;
    const int lane = t & 63;
    const int m0 = mb * 128;
    const int n0 = nb * 128;
    const int wm = (w & 1) * 64;
    const int wn = (w >> 1) * 64;
    const int lr = lane & 15;
    const int lk = (lane >> 4) * 8;

    // staging geometry: wave w, issue j covers LDS rows w*8+j*32 .. +8;
    // lane covers row w*8+j*32+(lane>>3), 16B chunk (lane&7).
    // Source column chunk pre-swizzled: chunk (lane&7)^(row&7), row&7=lane>>3.
    const int srow = w * 8 + (lane >> 3);
    const int scol = ((lane & 7) ^ (lane >> 3)) * 8;
    const unsigned short* ga = A  + (size_t)(m0 + srow) * 256 + scol;
    const unsigned short* gb = Bt + (size_t)(n0 + srow) * 256 + scol;
    unsigned short* lA = As + w * 512;   // + j*2048
    unsigned short* lB = Bs + w * 512;

    floatx4 acc[4][4] = {};

    for (int k0 = 0; k0 < 256; k0 += 64) {
        __syncthreads();   // previous tile's LDS reads complete before overwrite
        #pragma unroll
        for (int j = 0; j < 4; ++j) {
            gload_lds16(ga + (size_t)j * 32 * 256 + k0, lA + j * 2048);
            gload_lds16(gb + (size_t)j * 32 * 256 + k0, lB + j * 2048);
        }
        __syncthreads();   // vmcnt(0) drain: tile resident in LDS

        #pragma unroll
        for (int kk = 0; kk < 64; kk += 32) {
            half8 bf[4];
            #pragma unroll
            for (int nt = 0; nt < 4; ++nt) {
                const int row = wn + nt * 16 + lr;
                const int cb  = ((kk + lk) * 2) ^ ((row & 7) << 4);
                bf[nt] = *(const half8*)((const char*)Bs + row * 128 + cb);
            }
            #pragma unroll
            for (int mt = 0; mt < 4; ++mt) {
                const int row = wm + mt * 16 + lr;
                const int cb  = ((kk + lk) * 2) ^ ((row & 7) << 4);
                const half8 af = *(const half8*)((const char*)As + row * 128 + cb);
                #pragma unroll
                for (int nt = 0; nt < 4; ++nt)
                    acc[mt][nt] = __builtin_amdgcn_mfma_f32_16x16x32_f16(af, bf[nt], acc[mt][nt], 0, 0, 0);
            }
        }
    }

    // epilogue: C/D layout col = lane&15, row = (lane>>4)*4 + reg
    const int rbase = m0 + wm + (lane >> 4) * 4;
    #pragma unroll
    for (int nt = 0; nt < 4; ++nt) {
        const int col = n0 + wn + nt * 16 + lr;
        const float bb_ = bias[col];
        #pragma unroll
        for (int mt = 0; mt < 4; ++mt) {
            #pragma unroll
            for (int r = 0; r < 4; ++r) {
                const int row = rbase + mt * 16 + r;
                if (row < M) {
                    float val = acc[mt][nt][r] + bb_;
                    if (MODE == 2) val += residual[(size_t)row * ldc + col];
                    if (MODE == 0) {
                        ((unsigned short*)Cv)[(size_t)row * ldc + col] = f2h(val);
                    } else if (MODE == 3) {
                        const int b_ = row / NV;
                        const int s_ = row - b_ * NV;
                        const int h_ = col >> 5, d_ = col & 31;
                        ((unsigned short*)Cv)[(((size_t)b_ * 8 + h_) * NV + s_) * 32 + d_] = f2h(val);
                    } else {
                        ((float*)Cv)[(size_t)row * ldc + col] = val;
                    }
                }
            }
        }
    }
}

// Fused GEMM-V + GEMM-proj (independent, one dispatch to fill the machine).
//   [0, 832): v = v16 @ Wv + bv  -> per-head layout   (416 m x 2 n)
//   [832,1771): proj = q16 @ Wcat + bcat (row-major)  (313 m x 3 n)
// Bijective chunked XCD swizzle (m204).
__global__ __launch_bounds__(256) void gemm_fused12(
    const unsigned short* __restrict__ v16, const unsigned short* __restrict__ q16,
    const unsigned short* __restrict__ Wvt, const unsigned short* __restrict__ Wcatt,
    const float* __restrict__ bv, const float* __restrict__ bcat,
    unsigned short* __restrict__ vout, unsigned short* __restrict__ projout)
{
    __shared__ __align__(16) unsigned short As[128 * 64];
    __shared__ __align__(16) unsigned short Bs[128 * 64];
    // nwg = 1771: q = 221, r = 3
    const unsigned int xcd = blockIdx.x & 7u, kk = blockIdx.x >> 3;
    const unsigned int wg = (xcd < 3u ? xcd * 222u : 3u * 222u + (xcd - 3u) * 221u) + kk;
    if (wg < 832u) {
        gemm_body<3>(As, Bs, v16, BS * NV, Wvt, bv, vout, 256, nullptr,
                     (int)(wg >> 1), (int)(wg & 1));
    } else {
        const unsigned int b2 = wg - 832u;
        gemm_body<0>(As, Bs, q16, BS * NQ, Wcatt, bcat, projout, 384, nullptr,
                     (int)(b2 / 3u), (int)(b2 % 3u));
    }
}

// out = msda @ Wo + bo + query  (fp32 out). 1D grid 626 + chunked swizzle.
__global__ __launch_bounds__(256) void gemm_out(
    const unsigned short* __restrict__ msda, const unsigned short* __restrict__ Wot,
    const float* __restrict__ bo, float* __restrict__ out,
    const float* __restrict__ query)
{
    __shared__ __align__(16) unsigned short As[128 * 64];
    __shared__ __align__(16) unsigned short Bs[128 * 64];
    // nwg = 626: q = 78, r = 2
    const unsigned int xcd = blockIdx.x & 7u, kk = blockIdx.x >> 3;
    const unsigned int wg = (xcd < 2u ? xcd * 79u : 2u * 79u + (xcd - 2u) * 78u) + kk;
    gemm_body<2>(As, Bs, msda, BS * NQ, Wot, bo, out, 256, query,
                 (int)(wg >> 1), (int)(wg & 1));
}

// ---------------------------------------------------------------------------
// Fused softmax + bilinear sampling. Wide-gather restructure:
// wave = 16 queries x 1 head, lane = qi*4 + li. Each tap's 64 B is read by
// 4 lanes x uint4 (16 B) -> HALF the divergent wave-load instructions of the
// previous 8-lane x 8 B mapping (TA address-processing is the bottleneck:
// VALU cuts and L2-pinning both left dur unchanged across r3-r5).
// Phase A: lane li owns level li (all 4 points): ushort4 logits, uint4
// offsets, 4-lane softmax reduce. Entry (16 B): {off0, off1, pk(w0,w0),
// pk(w1,w1)}. Per-head v layout + XCD pin (h = bid&7) kept from r5.
// Block = 64 queries x one (b,h). Taps per-wave -> lgkm drain only.
// ---------------------------------------------------------------------------
__global__ __launch_bounds__(256) void msda_sample(
    const unsigned short* __restrict__ v,
    const unsigned short* __restrict__ proj,
    const float* __restrict__ rp,
    unsigned short* __restrict__ out)
{
    __shared__ __align__(16) unsigned int taps[4 * 2112];  // 4 waves * 16 q * 132 uints

    const unsigned int bid = blockIdx.x;
    const int h      = (int)(bid & 7u);          // -> XCD h
    const int b      = (int)((bid >> 3) & 3u);
    const int qchunk = (int)(bid >> 5);          // [0,157)
    const int wave = threadIdx.x >> 6;
    const int lane = threadIdx.x & 63;
    const int qi   = lane >> 2;                  // query slot within wave, 0..15
    const int li   = lane & 3;                   // level (phase A) / dim-block (phase B)
    const int q    = qchunk * 64 + wave * 16 + qi;
    const bool qok = q < NQ;
    const int rowq = b * NQ + (qok ? q : 0);
    const unsigned short* prow = proj + (size_t)rowq * 384;

    // ---- phase A: lane owns level li of (q,h): 4 logits + 4 points ----
    const ushort4 lg = *(const ushort4*)&prow[256 + h * 16 + li * 4];
    const float l0 = h2f(lg.x), l1 = h2f(lg.y), l2 = h2f(lg.z), l3 = h2f(lg.w);
    float mx = fmaxf(fmaxf(l0, l1), fmaxf(l2, l3));
    mx = fmaxf(mx, __shfl_xor(mx, 1));
    mx = fmaxf(mx, __shfl_xor(mx, 2));
    const float e0 = __expf(l0 - mx);
    const float e1 = __expf(l1 - mx);
    const float e2 = __expf(l2 - mx);
    const float e3 = __expf(l3 - mx);
    float ssum = (e0 + e1) + (e2 + e3);
    ssum += __shfl_xor(ssum, 1);
    ssum += __shfl_xor(ssum, 2);
    const float inv = 1.0f / ssum;
    const float ev[4] = {e0 * inv, e1 * inv, e2 * inv, e3 * inv};

    const int Wl = (li == 0) ? 100 : (li == 1) ? 50 : (li == 2) ? 25 : 13;
    const int st = (li == 0) ? 0 : (li == 1) ? 10000 : (li == 2) ? 12500 : 13125;
    const float fW = (float)Wl, fH = (float)Wl;

    const float2 rxy = *(const float2*)&rp[((size_t)rowq * 4 + li) * 2];

    // offsets for the 4 points of level li: 8 ushorts = uint4
    const uint4 offu = *(const uint4*)&prow[h * 32 + li * 8];
    const unsigned int opk[4] = {offu.x, offu.y, offu.z, offu.w};

    unsigned int* tbase = taps + wave * 2112 + qi * 132;

    #pragma unroll
    for (int p = 0; p < 4; ++p) {
        const float ox = h2f((unsigned short)(opk[p] & 0xFFFFu));
        const float oy = h2f((unsigned short)(opk[p] >> 16));
        const float aww = ev[p];
        const float x = fmaf(rxy.x, fW, ox) - 0.5f;
        const float y = fmaf(rxy.y, fH, oy) - 0.5f;
        const float x0f = floorf(x), y0f = floorf(y);
        const float fx = x - x0f, fy = y - y0f;
        const int ix = (int)x0f, iy = (int)y0f;
        const float wxv[2] = {1.f - fx, fx};
        const float wyv[2] = {1.f - fy, fy};

        unsigned int offv[4]; float wv_[4];
        #pragma unroll
        for (int tp = 0; tp < 4; ++tp) {
            const int dy = tp >> 1, dx = tp & 1;
            const int xi = ix + dx, yi = iy + dy;
            const bool ok = (xi >= 0) && (xi < Wl) && (yi >= 0) && (yi < Wl);
            const int cx = min(max(xi, 0), Wl - 1);
            const int cy = min(max(yi, 0), Wl - 1);
            offv[tp] = (unsigned int)(st + cy * Wl + cx) * 64u;   // bytes in (b,h) sub-table
            wv_[tp]  = ok ? wyv[dy] * wxv[dx] * aww : 0.f;
        }
        const uint4 eA = make_uint4(offv[0], offv[1], pk_f16(wv_[0], wv_[0]), pk_f16(wv_[1], wv_[1]));
        const uint4 eB = make_uint4(offv[2], offv[3], pk_f16(wv_[2], wv_[2]), pk_f16(wv_[3], wv_[3]));
        *(uint4*)&tbase[(li * 8 + p * 2) * 4]     = eA;
        *(uint4*)&tbase[(li * 8 + p * 2 + 1) * 4] = eB;
    }

    // per-wave LDS drain (taps produced and consumed by this wave only)
    asm volatile("s_waitcnt lgkmcnt(0)" ::: "memory");

    // ---- phase B: lane = qi*4+li owns dims li*8..li*8+7 of (q,h) ----
    const unsigned int lane_off = (unsigned int)li * 16u;
    const char* vbase = (const char*)v + ((size_t)b * 8 + h) * (size_t)NV * 64;
    const uint4* tp4 = (const uint4*)(taps + wave * 2112 + qi * 132);

    __half2 a0 = __floats2half2_rn(0.f, 0.f);
    __half2 a1 = a0, a2 = a0, a3 = a0;
    #pragma unroll 8
    for (int j = 0; j < 32; ++j) {
        const uint4 ee = tp4[j];
        const uint4 g0 = *(const uint4*)(vbase + (ee.x + lane_off));
        const uint4 g1 = *(const uint4*)(vbase + (ee.y + lane_off));
        __half2 w0, w1, t0, t1, t2, t3;
        __builtin_memcpy(&w0, &ee.z, 4);
        __builtin_memcpy(&w1, &ee.w, 4);
        __builtin_memcpy(&t0, &g0.x, 4);
        __builtin_memcpy(&t1, &g0.y, 4);
        __builtin_memcpy(&t2, &g0.z, 4);
        __builtin_memcpy(&t3, &g0.w, 4);
        a0 = __hfma2(t0, w0, a0);
        a1 = __hfma2(t1, w0, a1);
        a2 = __hfma2(t2, w0, a2);
        a3 = __hfma2(t3, w0, a3);
        __builtin_memcpy(&t0, &g1.x, 4);
        __builtin_memcpy(&t1, &g1.y, 4);
        __builtin_memcpy(&t2, &g1.z, 4);
        __builtin_memcpy(&t3, &g1.w, 4);
        a0 = __hfma2(t0, w1, a0);
        a1 = __hfma2(t1, w1, a1);
        a2 = __hfma2(t2, w1, a2);
        a3 = __hfma2(t3, w1, a3);
    }

    if (qok) {
        uint4 o;
        __builtin_memcpy(&o.x, &a0, 4);
        __builtin_memcpy(&o.y, &a1, 4);
        __builtin_memcpy(&o.z, &a2, 4);
        __builtin_memcpy(&o.w, &a3, 4);
        *(uint4*)&out[(size_t)rowq * 256 + h * 32 + li * 8] = o;
    }
}

// ---------------------------------------------------------------------------
// kernel_launch
// ---------------------------------------------------------------------------
extern "C" void kernel_launch(void* const* d_in, const int* in_sizes, int n_in,
                              void* d_out, int out_size, void* d_ws, size_t ws_size,
                              hipStream_t stream) {
    const float* query = (const float*)d_in[0];
    const float* value = (const float*)d_in[1];
    const float* rp    = (const float*)d_in[2];
    const float* Wv    = (const float*)d_in[4];
    const float* bv    = (const float*)d_in[5];
    const float* Woff  = (const float*)d_in[6];
    const float* boff  = (const float*)d_in[7];
    const float* Ww    = (const float*)d_in[8];
    const float* bw    = (const float*)d_in[9];
    const float* Wo    = (const float*)d_in[10];
    const float* bo    = (const float*)d_in[11];
    float* out = (float*)d_out;

    const int Mq = BS * NQ;   // 40000

    char* ws = (char*)d_ws;
    const size_t SZ_MSDA = (size_t)MQ_PAD * 256 * 2;   // padded rows
    const size_t SZ_VIN  = (size_t)MV_PAD * 256 * 2;   // f16 value, padded
    const size_t SZ_QIN  = (size_t)MQ_PAD * 256 * 2;   // f16 query, padded
    const size_t SZ_VPR  = (size_t)BS * NV * 256 * 2;  // projected v (per-head layout)
    const size_t SZ_PROJ = (size_t)Mq * 384 * 2;

    unsigned short* msda  = (unsigned short*)(ws);
    unsigned short* v16   = (unsigned short*)(ws + SZ_MSDA);
    unsigned short* q16   = (unsigned short*)(ws + SZ_MSDA + SZ_VIN);
    unsigned short* v_prj = (unsigned short*)(ws + SZ_MSDA + SZ_VIN + SZ_QIN);
    unsigned short* proj  = (unsigned short*)(ws + SZ_MSDA + SZ_VIN + SZ_QIN + SZ_VPR);
    char* wp = ws + SZ_MSDA + SZ_VIN + SZ_QIN + SZ_VPR + SZ_PROJ;
    unsigned short* Wvt   = (unsigned short*)(wp);
    unsigned short* Wcatt = (unsigned short*)(wp + 256 * 256 * 2);
    unsigned short* Wot   = (unsigned short*)(wp + 256 * 256 * 2 + 384 * 256 * 2);
    float*          bcat  = (float*)(wp + 256 * 256 * 2 + 384 * 256 * 2 + 256 * 256 * 2);

    // weights transpose/cast + value/query fp32->f16 streaming convert
    prep_convert<<<896 + CONV_BLOCKS, 256, 0, stream>>>(
        Wv, Woff, boff, Ww, bw, Wo, value, query,
        Wvt, Wcatt, Wot, bcat, v16, q16);

    // v_prj = v16 @ Wv + bv (f16, per-head layout) AND proj = q16 @ Wcat + bcat
    gemm_fused12<<<832 + 939, 256, 0, stream>>>(
        v16, q16, Wvt, Wcatt, bv, bcat, v_prj, proj);

    // softmax + sampling -> msda (f16). 157 qchunks x 4 b x 8 h, h = bid%8.
    msda_sample<<<157 * 32, 256, 0, stream>>>(v_prj, proj, rp, msda);

    // out = msda @ Wo + bo + query
    gemm_out<<<626, 256, 0, stream>>>(msda, Wot, bo, out, query);
}